// Round 10
// baseline (320.860 us; speedup 1.0000x reference)
//
#include <hip/hip_runtime.h>

namespace {
constexpr int B = 16, C = 19, H = 512, W = 512;
constexpr int TPB = 256;               // one column per thread (R4 geometry)
constexpr int HC = 128;                // output rows per block
constexpr int NHC = H / HC;            // 4
constexpr int NWB = W / TPB;           // 2
constexpr int NXCD = 8;
constexpr int TILES = B * NHC * NWB;   // 128 target tiles
constexpr int TPX = TILES / NXCD;      // 16
constexpr int NBLK = TILES * C;        // 2432 = 8*304 (XCD swizzle bijective)
constexpr int REPS = 4;                // DIAGNOSTIC: dispatch >190us -> kernel visible in rocprof top-5
constexpr float SCALE = 1.0f / (float)((long long)B * H * W * REPS);
}

__global__ void zero_out_kernel(float* out) { *out = 0.0f; }

__global__ __launch_bounds__(TPB) void edge_loss_kernel(
    const float* __restrict__ X,   // [B,C,H,W] f32
    const int*   __restrict__ T,   // [B,H,W] int32 labels
    float* __restrict__ out)
{
    // XCD swizzle: bid%8 -> XCD; 19 class-blocks of one tile adjacent on ONE XCD.
    int i = (int)blockIdx.x;
    const int xcd  = i & (NXCD - 1);
    const int j    = i >> 3;
    const int c    = j % C;
    const int tl   = j / C;
    const int tile = xcd * TPX + tl;
    const int wb   = tile & 1;
    const int hcb  = (tile >> 1) & (NHC - 1);
    const int b    = tile >> 3;
    const int h0   = hcb * HC;

    const int tid = (int)threadIdx.x;
    const int w   = wb * TPB + tid;            // global column 0..511

    // per-lane clamped halo offsets + border factors (persistent VGPRs: ~5)
    const int   wm = (w > 0)     ? (w - 1) : 0;
    const int   wp = (w < W - 1) ? (w + 1) : (W - 1);
    const float fl = (w > 0)     ? 1.0f : 0.0f;
    const float fr = (w < W - 1) ? 1.0f : 0.0f;

    // wave-uniform plane bases (SGPR) — row pointers advance uniformly
    const float* __restrict__ Xs = X + (size_t)(b * C + c) * (size_t)(H * W);
    const int*   __restrict__ Ts = T + (size_t)b * (size_t)(H * W);
    const int r0     = (hcb == 0) ? 0 : (h0 - 1);
    const int step1  = (hcb == 0) ? 0 : W;
    const bool lastc = (hcb == NHC - 1);

    float acc = 0.0f;

    // rolling separable-Sobel row aggregates (12 persistent VGPRs)
    float d0,s0,e0,u0, d1,s1,e1,u1, d2,s2,e2,u2;

#define LDROW(xrow, trow, D, S, E, U)                                \
    {                                                                \
        const float xm = (xrow)[wm] * fl;                            \
        const float x0 = (xrow)[w];                                  \
        const float xp = (xrow)[wp] * fr;                            \
        const float mm = ((trow)[wm] == c) ? fl  : 0.f;              \
        const float m0 = ((trow)[w]  == c) ? 1.f : 0.f;              \
        const float mp = ((trow)[wp] == c) ? fr  : 0.f;              \
        D = xp - xm;                                                 \
        S = fmaf(2.f, x0, xm + xp);                                  \
        E = mp - mm;                                                 \
        U = fmaf(2.f, m0, mm + mp);                                  \
    }

#define COMP(dA,sA,eA,uA, dB,eB, dC,sC,eC,uC)                        \
    {                                                                \
        const float gx = fmaf(2.f, dB, dA + dC);                     \
        const float gy = sC - sA;                                    \
        const float hx = fmaf(2.f, eB, eA + eC);                     \
        const float hy = uC - uA;                                    \
        const float dd = (fabsf(gx) + fabsf(gy))                     \
                       - (fabsf(hx) + fabsf(hy));                    \
        acc = fmaf(dd, dd, acc);                                     \
    }

#define BODY(dA,sA,eA,uA, dB,sB,eB,uB, dC,sC,eC,uC)                  \
    {                                                                \
        xr += W; tr += W;                                            \
        LDROW(xr, tr, dC, sC, eC, uC)                                \
        COMP(dA,sA,eA,uA, dB,eB, dC,sC,eC,uC)                        \
    }

    #pragma unroll 1
    for (int rep = 0; rep < REPS; ++rep) {
        const float* xr = Xs + (size_t)r0 * W;
        const int*   tr = Ts + (size_t)r0 * W;

        // prologue: row h0-1 (clamped; zeroed when hc==0) and row h0
        LDROW(xr, tr, d0, s0, e0, u0)
        if (hcb == 0) { d0 = s0 = e0 = u0 = 0.f; }
        xr += step1; tr += step1;
        LDROW(xr, tr, d1, s1, e1, u1)

        // 42 branch-free triples: outputs h0 .. h0+125
        for (int t = 0; t < 42; ++t) {
            BODY(d0,s0,e0,u0, d1,s1,e1,u1, d2,s2,e2,u2)
            BODY(d1,s1,e1,u1, d2,s2,e2,u2, d0,s0,e0,u0)
            BODY(d2,s2,e2,u2, d0,s0,e0,u0, d1,s1,e1,u1)
        }
        // output h0+126 (loads row h0+127, always in range)
        BODY(d0,s0,e0,u0, d1,s1,e1,u1, d2,s2,e2,u2)
        // output h0+127 (needs row h0+128; zero-pad on the last chunk)
        if (lastc) { d0 = s0 = e0 = u0 = 0.f; }
        else {
            xr += W; tr += W;
            LDROW(xr, tr, d0, s0, e0, u0)
        }
        COMP(d1,s1,e1,u1, d2,e2, d0,s0,e0,u0)
    }

#undef BODY
#undef COMP
#undef LDROW

    // reduce: wave shuffle -> LDS (4 waves) -> one atomic per block
    #pragma unroll
    for (int off = 32; off > 0; off >>= 1)
        acc += __shfl_down(acc, off, 64);

    __shared__ float wsum[TPB / 64];
    const int lane = tid & 63;
    const int wid  = tid >> 6;
    if (lane == 0) wsum[wid] = acc;
    __syncthreads();
    if (tid == 0)
        atomicAdd(out, (wsum[0] + wsum[1] + wsum[2] + wsum[3]) * SCALE);
}

extern "C" void kernel_launch(void* const* d_in, const int* in_sizes, int n_in,
                              void* d_out, int out_size, void* d_ws, size_t ws_size,
                              hipStream_t stream) {
    (void)in_sizes; (void)n_in; (void)d_ws; (void)ws_size; (void)out_size;
    const float* X = (const float*)d_in[0];
    const int*   T = (const int*)d_in[1];
    float* out = (float*)d_out;

    zero_out_kernel<<<1, 1, 0, stream>>>(out);
    edge_loss_kernel<<<NBLK, TPB, 0, stream>>>(X, T, out);
}

// Round 11
// 162.891 us; speedup vs baseline: 1.9698x; 1.9698x over previous
//
#include <hip/hip_runtime.h>

namespace {
constexpr int B = 16, C = 19, H = 512, W = 512;
constexpr int TPB = 256;               // thread t owns cols 2t, 2t+1 (full 512)
constexpr int HC = 64;                 // output rows per block
constexpr int NHC = H / HC;            // 8
constexpr int NXCD = 8;
constexpr int TILES = B * NHC;         // 128 (b,hc) target tiles
constexpr int TPX = TILES / NXCD;      // 16
constexpr int NBLK = TILES * C;        // 2432 = 8*304 (XCD swizzle bijective)
constexpr float SCALE = 1.0f / (float)((long long)B * H * W);
}

__global__ void zero_out_kernel(float* out) { *out = 0.0f; }

__global__ __launch_bounds__(TPB) void edge_loss_kernel(
    const float* __restrict__ X,   // [B,C,H,W] f32
    const int*   __restrict__ T,   // [B,H,W] int32 labels
    float* __restrict__ out)
{
    // XCD swizzle: bid%8 -> XCD; the 19 class-blocks of one (b,hc) tile are
    // adjacent on ONE XCD -> its T tile stays L2-resident, fetched ~once.
    int i = (int)blockIdx.x;
    const int xcd  = i & (NXCD - 1);
    const int j    = i >> 3;
    const int c    = j % C;
    const int tl   = j / C;
    const int tile = xcd * TPX + tl;
    const int b    = tile >> 3;            // / NHC
    const int hcb  = tile & (NHC - 1);
    const int h0   = hcb * HC;

    const int tid = (int)threadIdx.x;
    const int w0  = tid << 1;              // first of 2 owned columns

    // constant per-lane offsets (elements) + border factors
    const int   wml = (w0 > 0)     ? (w0 - 1) : 0;
    const int   wpr = (w0 + 2 < W) ? (w0 + 2) : (W - 1);
    const float fl  = (w0 > 0)     ? 1.0f : 0.0f;
    const float fr  = (w0 + 2 < W) ? 1.0f : 0.0f;

    // wave-uniform plane bases; row offset roff stays scalar (SGPR + SALU add)
    const float* __restrict__ Xs = X + (size_t)(b * C + c) * (size_t)(H * W);
    const int*   __restrict__ Ts = T + (size_t)b * (size_t)(H * W);
    int roff = ((hcb == 0) ? 0 : (h0 - 1)) * W;
    const int step1  = (hcb == 0) ? 0 : W;
    const bool lastc = (hcb == NHC - 1);

    float acc0 = 0.f, acc1 = 0.f;
    // rolling separable-Sobel row aggregates: buffer N, columns 0/1
    float d00,s00,e00,u00, d01,s01,e01,u01;
    float d10,s10,e10,u10, d11,s11,e11,u11;
    float d20,s20,e20,u20, d21,s21,e21,u21;

    // d = x[w+1]-x[w-1]; s = x[w-1]+2x[w]+x[w+1]; e,u same on one-hot mask.
    // gx = d(h-1)+2d(h)+d(h+1); gy = s(h+1)-s(h-1); hx,hy likewise from e,u.
#define LDROW(D0,S0,E0,U0, D1,S1,E1,U1)                                   \
    {                                                                     \
        const float2 xv = *reinterpret_cast<const float2*>(Xs + roff + w0); \
        const int2   tv = *reinterpret_cast<const int2*>(Ts + roff + w0);   \
        const float  xl = Xs[roff + wml] * fl;                            \
        const float  xr = Xs[roff + wpr] * fr;                            \
        const float  mL = (Ts[roff + wml] == c) ? fl : 0.f;               \
        const float  mR = (Ts[roff + wpr] == c) ? fr : 0.f;               \
        const float  m0 = (tv.x == c) ? 1.f : 0.f;                        \
        const float  m1 = (tv.y == c) ? 1.f : 0.f;                        \
        D0 = xv.y - xl;  D1 = xr - xv.x;                                  \
        S0 = fmaf(2.f, xv.x, xl + xv.y);                                  \
        S1 = fmaf(2.f, xv.y, xv.x + xr);                                  \
        E0 = m1 - mL;    E1 = mR - m0;                                    \
        U0 = fmaf(2.f, m0, mL + m1);                                      \
        U1 = fmaf(2.f, m1, m0 + mR);                                      \
    }

#define LDB(N) LDROW(d##N##0,s##N##0,e##N##0,u##N##0,                     \
                     d##N##1,s##N##1,e##N##1,u##N##1)
#define ZB(N)  { d##N##0=s##N##0=e##N##0=u##N##0=0.f;                     \
                 d##N##1=s##N##1=e##N##1=u##N##1=0.f; }

#define COMP2(A, Bq, Cq)                                                  \
    {                                                                     \
        float gx = fmaf(2.f, d##Bq##0, d##A##0 + d##Cq##0);               \
        float gy = s##Cq##0 - s##A##0;                                    \
        float hx = fmaf(2.f, e##Bq##0, e##A##0 + e##Cq##0);               \
        float hy = u##Cq##0 - u##A##0;                                    \
        float dd = (fabsf(gx) + fabsf(gy)) - (fabsf(hx) + fabsf(hy));     \
        acc0 = fmaf(dd, dd, acc0);                                        \
        gx = fmaf(2.f, d##Bq##1, d##A##1 + d##Cq##1);                     \
        gy = s##Cq##1 - s##A##1;                                          \
        hx = fmaf(2.f, e##Bq##1, e##A##1 + e##Cq##1);                     \
        hy = u##Cq##1 - u##A##1;                                          \
        dd = (fabsf(gx) + fabsf(gy)) - (fabsf(hx) + fabsf(hy));           \
        acc1 = fmaf(dd, dd, acc1);                                        \
    }

    // ---- prologue: row h0-1 (clamped; zeroed at top border) and row h0 ----
    LDB(0);
    if (hcb == 0) ZB(0);
    roff += step1;
    LDB(1);
    roff += W;

    // ---- 63 branch-free outputs h0..h0+62 (loads rows h0+1..h0+63) ----
    for (int t = 0; t < 21; ++t) {
        LDB(2); roff += W; COMP2(0, 1, 2);
        LDB(0); roff += W; COMP2(1, 2, 0);
        LDB(1); roff += W; COMP2(2, 0, 1);
    }
    // ---- final output h0+63 needs row h0+64 (zero-pad on last chunk) ----
    if (lastc) { ZB(2); }
    else       { LDB(2); }
    COMP2(0, 1, 2);

#undef LDROW
#undef LDB
#undef ZB
#undef COMP2

    // ---- reduce: wave shuffle -> LDS (4 waves) -> one atomic per block ----
    float a = acc0 + acc1;
    #pragma unroll
    for (int off = 32; off > 0; off >>= 1)
        a += __shfl_down(a, off, 64);

    __shared__ float wsum[TPB / 64];
    const int lane = tid & 63;
    const int wid  = tid >> 6;
    if (lane == 0) wsum[wid] = a;
    __syncthreads();
    if (tid == 0)
        atomicAdd(out, (wsum[0] + wsum[1] + wsum[2] + wsum[3]) * SCALE);
}

extern "C" void kernel_launch(void* const* d_in, const int* in_sizes, int n_in,
                              void* d_out, int out_size, void* d_ws, size_t ws_size,
                              hipStream_t stream) {
    (void)in_sizes; (void)n_in; (void)d_ws; (void)ws_size; (void)out_size;
    const float* X = (const float*)d_in[0];
    const int*   T = (const int*)d_in[1];
    float* out = (float*)d_out;

    zero_out_kernel<<<1, 1, 0, stream>>>(out);
    edge_loss_kernel<<<NBLK, TPB, 0, stream>>>(X, T, out);
}

// Round 12
// 122.919 us; speedup vs baseline: 2.6103x; 1.3252x over previous
//
#include <hip/hip_runtime.h>

namespace {
constexpr int B = 16, C = 19, H = 512, W = 512;
constexpr int TPB = 512;               // 8 waves; thread t owns col t (full W)
constexpr int HC = 64;                 // output rows per block
constexpr int NHC = H / HC;            // 8
constexpr int NXCD = 8;
constexpr int TILES = B * NHC;         // 128 (b,hc) target tiles
constexpr int TPX = TILES / NXCD;      // 16
constexpr int NBLK = TILES * C;        // 2432 = 8*304 (XCD swizzle bijective)
constexpr int SLOTS = 16;              // LDS ring rows (16 x 2KB = 32KB)
constexpr int TROFF_MAX = (H - 1) * W;
constexpr float SCALE = 1.0f / (float)((long long)B * H * W);
}

__global__ void zero_out_kernel(float* out) { *out = 0.0f; }

__global__ __launch_bounds__(TPB, 8) void edge_loss_kernel(
    const float* __restrict__ X,   // [B,C,H,W] f32
    const int*   __restrict__ T,   // [B,H,W] int32 labels
    float* __restrict__ out)
{
    // XCD swizzle: bid%8 -> XCD; the 19 class-blocks of one (b,hc) tile are
    // adjacent on ONE XCD -> its T tile stays L2-resident.
    int i = (int)blockIdx.x;
    const int xcd  = i & (NXCD - 1);
    const int j    = i >> 3;
    const int c    = j % C;
    const int tl   = j / C;
    const int tile = xcd * TPX + tl;
    const int b    = tile >> 3;            // / NHC
    const int hcb  = tile & (NHC - 1);
    const int h0   = hcb * HC;
    const bool lastc = (hcb == NHC - 1);

    const int tid  = (int)threadIdx.x;
    const int w    = tid;                  // owned column
    const int wv   = tid >> 6;             // wave id 0..7
    const int lane = tid & 63;
    const int scol = (wv & 1) * 256 + lane * 4;   // staging columns (float4)

    // clamped halo columns + border factors (constant per thread)
    const int   wmc = (w > 0)     ? (w - 1) : 0;
    const int   wpc = (w < W - 1) ? (w + 1) : (W - 1);
    const float fl  = (w > 0)     ? 1.0f : 0.0f;
    const float fr  = (w < W - 1) ? 1.0f : 0.0f;

    const float* __restrict__ Xs = X + (size_t)(b * C + c) * (size_t)(H * W);
    const int*   __restrict__ Ts = T + (size_t)b * (size_t)(H * W);

    __shared__ float lds_x[SLOTS][W];      // 32 KB ring of X rows
    __shared__ float wsum[TPB / 64];

    // agg ring: agg(row r) lives at index r&3; all indices literal post-expand
    float da[4], sa[4], ea[4], ua[4];
    float acc = 0.0f;

    // ---- prologue: stage local rows [-4..7] (or zeros for row -1) ----
    {
        float4 s0, s1, s2;
        bool up = (hcb != 0);
        if (up) {
            const int gr = h0 - 4 + (wv >> 1);
            s0 = *reinterpret_cast<const float4*>(Xs + (size_t)gr * W + scol);
        }
        {
            const int gr = h0 + (wv >> 1);
            s1 = *reinterpret_cast<const float4*>(Xs + (size_t)gr * W + scol);
        }
        {
            const int gr = h0 + 4 + (wv >> 1);
            s2 = *reinterpret_cast<const float4*>(Xs + (size_t)gr * W + scol);
        }
        if (up) {
            *reinterpret_cast<float4*>(&lds_x[12 + (wv >> 1)][scol]) = s0;
        } else {
            lds_x[15][tid] = 0.0f;         // zero-pad row -1
        }
        *reinterpret_cast<float4*>(&lds_x[0 + (wv >> 1)][scol]) = s1;
        *reinterpret_cast<float4*>(&lds_x[4 + (wv >> 1)][scol]) = s2;
    }
    __syncthreads();

    // T row offset: wave-uniform int, advanced by SALU; clamped at image end
    int troff = (hcb ? (h0 - 1) : 0) * W;

#define LDAGG_P(IDX, SLOT, TOFF)                                             \
    {                                                                        \
        const float xm = lds_x[SLOT][wmc] * fl;                              \
        const float x0 = lds_x[SLOT][w];                                     \
        const float xp = lds_x[SLOT][wpc] * fr;                              \
        const int tm = Ts[(TOFF) + wmc];                                     \
        const int t0 = Ts[(TOFF) + w];                                       \
        const int tp = Ts[(TOFF) + wpc];                                     \
        const float mm = (tm == c) ? fl : 0.f;                               \
        const float m0 = (t0 == c) ? 1.f : 0.f;                              \
        const float mp = (tp == c) ? fr : 0.f;                               \
        da[IDX] = xp - xm; sa[IDX] = fmaf(2.f, x0, xm + xp);                 \
        ea[IDX] = mp - mm; ua[IDX] = fmaf(2.f, m0, mm + mp);                 \
    }

    // aggs for local rows -1 (idx 3, slot 15) and 0 (idx 0, slot 0)
    LDAGG_P(3, 15, troff)
    if (hcb == 0) { da[3] = sa[3] = ea[3] = ua[3] = 0.f; }
    LDAGG_P(0, 0, h0 * W)
    troff = (h0 + 1) * W;

    // sub-step K of phase: aggregate local row 4q+1+K from slot RSLOT,
    // emit output row 4q+K.  d/s = input col-diff/col-sum; e/u = mask plane.
    // gx = d(-1)+2d(0)+d(+1); gy = s(+1)-s(-1); hx,hy likewise.
#define SUB(K, RSLOT, ZFIX)                                                  \
    {                                                                        \
        const float xm = lds_x[RSLOT][wmc] * fl;                             \
        const float x0 = lds_x[RSLOT][w];                                    \
        const float xp = lds_x[RSLOT][wpc] * fr;                             \
        const int tm = Ts[troff + wmc];                                      \
        const int t0 = Ts[troff + w];                                        \
        const int tp = Ts[troff + wpc];                                      \
        troff += W; if (troff > TROFF_MAX) troff = TROFF_MAX;                \
        const float mm = (tm == c) ? fl : 0.f;                               \
        const float m0 = (t0 == c) ? 1.f : 0.f;                              \
        const float mp = (tp == c) ? fr : 0.f;                               \
        float dn = xp - xm, sn = fmaf(2.f, x0, xm + xp);                     \
        float en = mp - mm, un = fmaf(2.f, m0, mm + mp);                     \
        if (ZFIX && lastzero) { dn = sn = en = un = 0.f; }                   \
        da[(K + 1) & 3] = dn; sa[(K + 1) & 3] = sn;                          \
        ea[(K + 1) & 3] = en; ua[(K + 1) & 3] = un;                          \
        const float gx = fmaf(2.f, da[K & 3], da[(K + 3) & 3] + dn);         \
        const float gy = sn - sa[(K + 3) & 3];                               \
        const float hx = fmaf(2.f, ea[K & 3], ea[(K + 3) & 3] + en);         \
        const float hy = un - ua[(K + 3) & 3];                               \
        const float dd = (fabsf(gx) + fabsf(gy)) - (fabsf(hx) + fabsf(hy));  \
        acc = fmaf(dd, dd, acc);                                             \
    }

    // phase J (of qq): issue next-chunk load EARLY, compute 4 rows from LDS,
    // write staged chunk LATE (slots 4J+8..4J+11 never collide with reads
    // 4J-1..4J+4 mod 16), one barrier.
#define PHASE(J, ZF)                                                         \
    {                                                                        \
        float4 st;                                                           \
        {                                                                    \
            int gr = h0 + qq * 16 + 4 * (J) + 8 + (wv >> 1);                 \
            if (gr > H - 1) gr = H - 1;                                      \
            st = *reinterpret_cast<const float4*>(                           \
                     Xs + (size_t)gr * W + scol);                            \
        }                                                                    \
        SUB(0, (4 * (J) + 1) & 15, 0)                                        \
        SUB(1, (4 * (J) + 2) & 15, 0)                                        \
        SUB(2, (4 * (J) + 3) & 15, 0)                                        \
        SUB(3, (4 * (J) + 4) & 15, ZF)                                       \
        *reinterpret_cast<float4*>(                                          \
            &lds_x[(4 * (J) + 8 + (wv >> 1)) & 15][scol]) = st;              \
        __syncthreads();                                                     \
    }

    for (int qq = 0; qq < 4; ++qq) {       // 16 phases, 64 output rows
        const bool lastzero = lastc && (qq == 3);
        PHASE(0, 0)
        PHASE(1, 0)
        PHASE(2, 0)
        PHASE(3, 1)
        (void)lastzero;
    }

#undef PHASE
#undef SUB
#undef LDAGG_P

    // ---- reduce: wave shuffle -> LDS (8 waves) -> one atomic per block ----
    #pragma unroll
    for (int off = 32; off > 0; off >>= 1)
        acc += __shfl_down(acc, off, 64);

    if (lane == 0) wsum[wv] = acc;
    __syncthreads();
    if (tid == 0) {
        float s = 0.f;
        #pragma unroll
        for (int k = 0; k < TPB / 64; ++k) s += wsum[k];
        atomicAdd(out, s * SCALE);
    }
}

extern "C" void kernel_launch(void* const* d_in, const int* in_sizes, int n_in,
                              void* d_out, int out_size, void* d_ws, size_t ws_size,
                              hipStream_t stream) {
    (void)in_sizes; (void)n_in; (void)d_ws; (void)ws_size; (void)out_size;
    const float* X = (const float*)d_in[0];
    const int*   T = (const int*)d_in[1];
    float* out = (float*)d_out;

    zero_out_kernel<<<1, 1, 0, stream>>>(out);
    edge_loss_kernel<<<NBLK, TPB, 0, stream>>>(X, T, out);
}